// Round 9
// baseline (453.917 us; speedup 1.0000x reference)
//
#include <hip/hip_runtime.h>
#include <hip/hip_bf16.h>
#include <cstdint>

#define NN 8192
#define EE 128
#define AA 8
#define QSCALE 0.08838834764831845f   // 1/sqrt(128)
#define KVW 8                          // waves per block = KV partitions
#define KVLEN (NN / KVW)               // 1024 cols per wave
#define NIT (KVLEN / 64)               // 16 chunks per wave
#define NW (NN / 64)                   // 128 mask words per row

typedef __attribute__((ext_vector_type(8))) short bf16x8;
typedef __attribute__((ext_vector_type(4))) short bf16x4;
typedef __attribute__((ext_vector_type(4))) float f32x4;
typedef unsigned short u16;
typedef unsigned int u32;
typedef unsigned long long u64;

__device__ __forceinline__ u16 bf16_bits(float x) {
    union { float f; u32 u; } v; v.f = x;
    u32 r = v.u + 0x7fffu + ((v.u >> 16) & 1u);   // RNE
    return (u16)(r >> 16);
}

// ---------------------------------------------------------------------------
// Kernel 0: pack adj (int32 {0,1}, 256MB) into a bitmask (8MB).
// ---------------------------------------------------------------------------
__global__ __launch_bounds__(256) void k_adjmask(
    const int* __restrict__ adj, u64* __restrict__ msk)
{
    const u32 gwave  = (blockIdx.x * 256 + threadIdx.x) >> 6;
    const u32 nwaves = (gridDim.x * 256) >> 6;
    const int lane   = threadIdx.x & 63;
    const size_t nwords = (size_t)NN * NW;   // 1,048,576
    for (size_t w = (size_t)gwave * 4; w < nwords; w += (size_t)nwaves * 4) {
        u64 b[4];
        #pragma unroll
        for (int u = 0; u < 4; ++u)
            b[u] = __ballot(adj[(w + u) * 64 + lane] != 0);
        if (lane == 0) {
            *reinterpret_cast<ulonglong2*>(&msk[w])     = ulonglong2{b[0], b[1]};
            *reinterpret_cast<ulonglong2*>(&msk[w + 2]) = ulonglong2{b[2], b[3]};
        }
    }
}

// ---------------------------------------------------------------------------
// Kernel 1: h = relu(state@w1+b1)@w2+b2 ; q = (h@wq)/sqrt(E) ; k = h@wk
// Writes q,k as bf16 [N][E] and hT as bf16 [E][N].
// ---------------------------------------------------------------------------
__global__ __launch_bounds__(128) void k_mlp(
    const float* __restrict__ state,
    const float* __restrict__ w1, const float* __restrict__ b1,
    const float* __restrict__ w2, const float* __restrict__ b2,
    const float* __restrict__ wq, const float* __restrict__ wk,
    u16* __restrict__ qb, u16* __restrict__ kb, u16* __restrict__ hT)
{
    __shared__ float st[16][EE + 1];   // state tile, then reused for h
    __shared__ float h1[16][EE + 1];
    const int t  = threadIdx.x;
    const int rg = t >> 4;            // 0..7
    const int ec = (t & 15) * 8;      // col base
    const int ra = rg * 2, rb = ra + 1;
    const int r0b = blockIdx.x * 16;

    #pragma unroll
    for (int r = 0; r < 16; ++r)
        st[r][t] = state[(size_t)(r0b + r) * EE + t];
    __syncthreads();

    // stage 1: h1 = relu(st@w1 + b1)
    {
        float a0[8], a1[8];
        #pragma unroll
        for (int j = 0; j < 8; ++j) { float b = b1[ec + j]; a0[j] = b; a1[j] = b; }
        for (int s = 0; s < EE; ++s) {
            float x0 = st[ra][s], x1 = st[rb][s];
            const float* wrow = w1 + s * EE + ec;
            #pragma unroll
            for (int j = 0; j < 8; ++j) { float w = wrow[j]; a0[j] = fmaf(x0, w, a0[j]); a1[j] = fmaf(x1, w, a1[j]); }
        }
        __syncthreads();
        #pragma unroll
        for (int j = 0; j < 8; ++j) { h1[ra][ec + j] = fmaxf(a0[j], 0.f); h1[rb][ec + j] = fmaxf(a1[j], 0.f); }
    }
    __syncthreads();

    // stage 2: h = h1@w2 + b2
    float hva[8], hvb[8];
    {
        float a0[8], a1[8];
        #pragma unroll
        for (int j = 0; j < 8; ++j) { float b = b2[ec + j]; a0[j] = b; a1[j] = b; }
        for (int s = 0; s < EE; ++s) {
            float x0 = h1[ra][s], x1 = h1[rb][s];
            const float* wrow = w2 + s * EE + ec;
            #pragma unroll
            for (int j = 0; j < 8; ++j) { float w = wrow[j]; a0[j] = fmaf(x0, w, a0[j]); a1[j] = fmaf(x1, w, a1[j]); }
        }
        #pragma unroll
        for (int j = 0; j < 8; ++j) {
            st[ra][ec + j] = a0[j]; st[rb][ec + j] = a1[j];
            hva[j] = a0[j]; hvb[j] = a1[j];
        }
    }
    __syncthreads();

    // stage 3: q = (h@wq)*QSCALE, k = h@wk
    {
        float q0[8], q1[8], k0[8], k1[8];
        #pragma unroll
        for (int j = 0; j < 8; ++j) { q0[j] = 0.f; q1[j] = 0.f; k0[j] = 0.f; k1[j] = 0.f; }
        for (int s = 0; s < EE; ++s) {
            float x0 = st[ra][s], x1 = st[rb][s];
            const float* wqr = wq + s * EE + ec;
            const float* wkr = wk + s * EE + ec;
            #pragma unroll
            for (int j = 0; j < 8; ++j) {
                float a = wqr[j], b = wkr[j];
                q0[j] = fmaf(x0, a, q0[j]); q1[j] = fmaf(x1, a, q1[j]);
                k0[j] = fmaf(x0, b, k0[j]); k1[j] = fmaf(x1, b, k1[j]);
            }
        }
        bf16x8 vq0, vq1, vk0, vk1;
        #pragma unroll
        for (int j = 0; j < 8; ++j) {
            vq0[j] = (short)bf16_bits(q0[j] * QSCALE);
            vq1[j] = (short)bf16_bits(q1[j] * QSCALE);
            vk0[j] = (short)bf16_bits(k0[j]);
            vk1[j] = (short)bf16_bits(k1[j]);
        }
        *reinterpret_cast<bf16x8*>(qb + (size_t)(r0b + ra) * EE + ec) = vq0;
        *reinterpret_cast<bf16x8*>(qb + (size_t)(r0b + rb) * EE + ec) = vq1;
        *reinterpret_cast<bf16x8*>(kb + (size_t)(r0b + ra) * EE + ec) = vk0;
        *reinterpret_cast<bf16x8*>(kb + (size_t)(r0b + rb) * EE + ec) = vk1;
    }

    #pragma unroll
    for (int j = 0; j < 8; ++j) {
        u32 pack = (u32)bf16_bits(hva[j]) | ((u32)bf16_bits(hvb[j]) << 16);
        *reinterpret_cast<u32*>(hT + (size_t)(ec + j) * NN + r0b + ra) = pack;
    }
}

// ---------------------------------------------------------------------------
// Kernel 2: flash-style masked attention, block-level KV split.
// SWAPPED QK^T: sv = mfma(K_frag, Q_frag) -> lane holds S[q=lane&15][k].
// Softmax is lane-local (in-lane reduce + shfl_xor 16/32). PV A-frag is the
// lane's own P values (k-permutation absorbed into hT B-load addresses).
// NO LDS in the main loop -> no drains/fences, compiler free to pipeline.
// ---------------------------------------------------------------------------
__global__ __launch_bounds__(512, 4) void k_attn(
    const u16* __restrict__ qb, const u16* __restrict__ kb,
    const u16* __restrict__ hT, const u64* __restrict__ msk,
    float* __restrict__ agg)
{
    __shared__ float lds_acc[KVW][16][EE];   // 64 KB, written only at the end
    __shared__ float lds_m[KVW][16];
    __shared__ float lds_l[KVW][16];

    const int tid  = threadIdx.x;
    const int wv   = tid >> 6;
    const int lane = tid & 63;
    const int l15  = lane & 15;
    const int g    = lane >> 4;
    const int qbase = blockIdx.x * 16;
    const int kv0   = wv * KVLEN;

    // Q fragments (B-operand): lane holds Q[qbase+l15][ks*32+8g..+8]
    bf16x8 qf[4];
    #pragma unroll
    for (int ks = 0; ks < 4; ++ks)
        qf[ks] = *reinterpret_cast<const bf16x8*>(qb + (size_t)(qbase + l15) * EE + ks * 32 + g * 8);

    f32x4 acc[8];
    #pragma unroll
    for (int et = 0; et < 8; ++et) acc[et] = f32x4{0.f, 0.f, 0.f, 0.f};
    float m = -__builtin_inff(), l = 0.f;   // per-lane: q = l15 (4 g-copies in sync)

    const u64* mrow = msk + (size_t)(qbase + l15) * NW + (kv0 >> 6);

    for (int cc = 0; cc < NIT; ++cc) {
        const int c0 = kv0 + cc * 64;
        const u64 mw = mrow[cc];   // mask word for (q=l15, this 64-col chunk)

        // S^T: sv[nt][j] = S[q=l15][k = nt*16 + 4g + j]
        f32x4 sv[4];
        #pragma unroll
        for (int nt = 0; nt < 4; ++nt) sv[nt] = f32x4{0.f, 0.f, 0.f, 0.f};
        #pragma unroll
        for (int nt = 0; nt < 4; ++nt) {
            #pragma unroll
            for (int ks = 0; ks < 4; ++ks) {
                bf16x8 bk = *reinterpret_cast<const bf16x8*>(
                    kb + (size_t)(c0 + nt * 16 + l15) * EE + ks * 32 + g * 8);
                sv[nt] = __builtin_amdgcn_mfma_f32_16x16x32_bf16(bk, qf[ks], sv[nt], 0, 0, 0);
            }
        }
        // mask + in-lane row max over this lane's 16 k's
        float ms[4][4];
        float rm = -__builtin_inff();
        #pragma unroll
        for (int nt = 0; nt < 4; ++nt) {
            #pragma unroll
            for (int j = 0; j < 4; ++j) {
                float v = ((mw >> (nt * 16 + 4 * g + j)) & 1ull)
                              ? sv[nt][j] : -__builtin_inff();
                ms[nt][j] = v;
                rm = fmaxf(rm, v);
            }
        }
        // cross-g: lanes (l15, g=0..3) hold disjoint k's of the same q-row
        rm = fmaxf(rm, __shfl_xor(rm, 16));
        rm = fmaxf(rm, __shfl_xor(rm, 32));
        const float mn2 = fmaxf(m, rm);
        const float alpha = (mn2 == m) ? 1.f : __expf(m - mn2);
        m = mn2;

        float rs = 0.f;
        u16 pb[4][4];
        #pragma unroll
        for (int nt = 0; nt < 4; ++nt) {
            #pragma unroll
            for (int j = 0; j < 4; ++j) {
                float pv = (mn2 == -__builtin_inff()) ? 0.f : __expf(ms[nt][j] - mn2);
                rs += pv;
                pb[nt][j] = bf16_bits(pv);
            }
        }
        rs += __shfl_xor(rs, 16);
        rs += __shfl_xor(rs, 32);
        l = l * alpha + rs;

        // P A-frags, fully lane-local: pa[ks][i] = pb[2ks + (i>>2)][i&3]
        bf16x8 pa[2];
        #pragma unroll
        for (int ks = 0; ks < 2; ++ks) {
            #pragma unroll
            for (int i = 0; i < 4; ++i) {
                pa[ks][i]     = (short)pb[2 * ks][i];
                pa[ks][i + 4] = (short)pb[2 * ks + 1][i];
            }
        }
        // alpha for acc rows (acc row = 4g+j, alpha lives at lane l15 = q)
        f32x4 avv;
        #pragma unroll
        for (int j = 0; j < 4; ++j) avv[j] = __shfl(alpha, 4 * g + j);

        // PV: acc += P @ h_chunk.  B-frag k-permutation matches pa:
        // kelem 8g+i  <->  phys k = (2ks + (i>>2))*16 + 4g + (i&3)
        #pragma unroll
        for (int et = 0; et < 8; ++et) {
            acc[et] = acc[et] * avv;
            #pragma unroll
            for (int ks = 0; ks < 2; ++ks) {
                const u16* hb = hT + (size_t)(et * 16 + l15) * NN + c0 + 32 * ks + 4 * g;
                bf16x4 lo = *reinterpret_cast<const bf16x4*>(hb);
                bf16x4 hi = *reinterpret_cast<const bf16x4*>(hb + 16);
                bf16x8 bh;
                #pragma unroll
                for (int i = 0; i < 4; ++i) { bh[i] = lo[i]; bh[i + 4] = hi[i]; }
                acc[et] = __builtin_amdgcn_mfma_f32_16x16x32_bf16(pa[ks], bh, acc[et], 0, 0, 0);
            }
        }
    }

    // write partials
    #pragma unroll
    for (int et = 0; et < 8; ++et)
        #pragma unroll
        for (int j = 0; j < 4; ++j)
            lds_acc[wv][g * 4 + j][et * 16 + l15] = acc[et][j];
    if (g == 0) {
        lds_m[wv][l15] = m;
        lds_l[wv][l15] = l;
    }
    __syncthreads();

    // combine 8 partials: wave wv owns rows {2wv, 2wv+1}; lane owns 2 cols
    #pragma unroll
    for (int rr = 0; rr < 2; ++rr) {
        const int r = wv * 2 + rr;
        float mp[KVW], M = -__builtin_inff();
        #pragma unroll
        for (int p = 0; p < KVW; ++p) { mp[p] = lds_m[p][r]; M = fmaxf(M, mp[p]); }
        float ep[KVW], L = 0.f;
        #pragma unroll
        for (int p = 0; p < KVW; ++p) { ep[p] = __expf(mp[p] - M); L += lds_l[p][r] * ep[p]; }
        const float invL = 1.f / L;
        #pragma unroll
        for (int cs = 0; cs < 2; ++cs) {
            const int c = lane + cs * 64;
            float s = 0.f;
            #pragma unroll
            for (int p = 0; p < KVW; ++p) s += lds_acc[p][r][c] * ep[p];
            agg[(size_t)(qbase + r) * EE + c] = s * invL;
        }
    }
}

// ---------------------------------------------------------------------------
// Kernel 3: out = relu(agg@wh1+bh1)@wh2 + bh2
// ---------------------------------------------------------------------------
__global__ __launch_bounds__(128) void k_head(
    const float* __restrict__ agg,
    const float* __restrict__ wh1, const float* __restrict__ bh1,
    const float* __restrict__ wh2, const float* __restrict__ bh2,
    float* __restrict__ out)
{
    __shared__ float ag[16][EE + 1];
    __shared__ float h2[16][EE + 1];
    const int t  = threadIdx.x;
    const int rg = t >> 4;
    const int ec = (t & 15) * 8;
    const int ra = rg * 2, rb = ra + 1;
    const int r0b = blockIdx.x * 16;

    #pragma unroll
    for (int r = 0; r < 16; ++r)
        ag[r][t] = agg[(size_t)(r0b + r) * EE + t];
    __syncthreads();
    {
        float a0[8], a1[8];
        #pragma unroll
        for (int j = 0; j < 8; ++j) { float b = bh1[ec + j]; a0[j] = b; a1[j] = b; }
        for (int s = 0; s < EE; ++s) {
            float x0 = ag[ra][s], x1 = ag[rb][s];
            const float* wrow = wh1 + s * EE + ec;
            #pragma unroll
            for (int j = 0; j < 8; ++j) { float w = wrow[j]; a0[j] = fmaf(x0, w, a0[j]); a1[j] = fmaf(x1, w, a1[j]); }
        }
        #pragma unroll
        for (int j = 0; j < 8; ++j) { h2[ra][ec + j] = fmaxf(a0[j], 0.f); h2[rb][ec + j] = fmaxf(a1[j], 0.f); }
    }
    __syncthreads();
    const int r = t >> 3, a = t & 7;
    float o = bh2[a];
    for (int s = 0; s < EE; ++s) o = fmaf(h2[r][s], wh2[s * AA + a], o);
    out[(size_t)(r0b + r) * AA + a] = o;
}

// ---------------------------------------------------------------------------
extern "C" void kernel_launch(void* const* d_in, const int* in_sizes, int n_in,
                              void* d_out, int out_size, void* d_ws, size_t ws_size,
                              hipStream_t stream)
{
    (void)in_sizes; (void)n_in; (void)out_size; (void)ws_size;
    const float* state = (const float*)d_in[0];
    const int*   adj   = (const int*)d_in[1];
    const float* w1  = (const float*)d_in[2];
    const float* b1  = (const float*)d_in[3];
    const float* w2  = (const float*)d_in[4];
    const float* b2  = (const float*)d_in[5];
    const float* wq  = (const float*)d_in[6];
    const float* wk  = (const float*)d_in[7];
    const float* wh1 = (const float*)d_in[8];
    const float* bh1 = (const float*)d_in[9];
    const float* wh2 = (const float*)d_in[10];
    const float* bh2 = (const float*)d_in[11];
    float* out = (float*)d_out;

    char* ws = (char*)d_ws;
    u16*  qb  = (u16*)ws;                                  //  0..2 MB
    u16*  kb  = (u16*)(ws + (size_t)NN * EE * 2);          //  2..4 MB
    u16*  hT  = (u16*)(ws + (size_t)NN * EE * 4);          //  4..6 MB
    float* agg = (float*)(ws + (size_t)NN * EE * 6);       //  6..10 MB
    u64*  msk = (u64*)(ws + (size_t)NN * EE * 6 + (size_t)NN * EE * 4); // 10..18 MB

    k_mlp    <<<NN / 16, 128, 0, stream>>>(state, w1, b1, w2, b2, wq, wk, qb, kb, hT);
    k_adjmask<<<2048, 256, 0, stream>>>(adj, msk);
    k_attn   <<<NN / 16, 512, 0, stream>>>(qb, kb, hT, msk, agg);
    k_head   <<<NN / 16, 128, 0, stream>>>(agg, wh1, bh1, wh2, bh2, out);
}